// Round 1
// baseline (1334.317 us; speedup 1.0000x reference)
//
#include <hip/hip_runtime.h>
#include <math.h>

#define N_RELS 1315
#define NB 65536
#define NNZV (1 << 20)
#define FEATD 768

// ---------------- precompute: P tables, Prel, b' ----------------
__global__ void k_prep(const float* __restrict__ rel_emb,
                       const float* __restrict__ W_in, const float* __restrict__ b_in,
                       const float* __restrict__ W_out, const float* __restrict__ b_out,
                       const float* __restrict__ W_ent, const float* __restrict__ b_ent,
                       const float* __restrict__ W_rel, const float* __restrict__ b_rel,
                       float* __restrict__ Pcat, float* __restrict__ Prel,
                       float* __restrict__ bprime)
{
    // C[d][o][t] = sum_j W_ent[o][768 + d*32 + j] * W{in,out}[j][t]
    __shared__ float C[2][32][33];
    const int tid = threadIdx.x;
    for (int idx = tid; idx < 2 * 32 * 32; idx += 256) {
        int d = idx >> 10, o = (idx >> 5) & 31, t = idx & 31;
        const float* W  = d ? W_out : W_in;
        const float* we = W_ent + o * 832 + 768 + d * 32;
        float s = 0.f;
        #pragma unroll
        for (int j = 0; j < 32; ++j) s += we[j] * W[j * 32 + t];
        C[d][o][t] = s;
    }
    __syncthreads();

    const int row8 = blockIdx.x * 8 + (tid >> 5);
    const int o = tid & 31;
    if (row8 < 2 * N_RELS) {
        // P[d][r][o] = sum_t rel_emb[r][t] * C[d][o][t]
        const int d = (row8 >= N_RELS) ? 1 : 0;
        const int r = row8 - d * N_RELS;
        const float* re = rel_emb + r * 32;
        float s = 0.f;
        #pragma unroll
        for (int t = 0; t < 32; ++t) s += re[t] * C[d][o][t];
        Pcat[row8 * 32 + o] = s;
    } else if (row8 < 3 * N_RELS) {
        // Prel[r] = normalize(rel_emb[r] @ W_rel.T + b_rel)
        const int r = row8 - 2 * N_RELS;
        const float* re = rel_emb + r * 32;
        float s = b_rel[o];
        #pragma unroll
        for (int j = 0; j < 32; ++j) s += W_rel[o * 32 + j] * re[j];
        float sq = s * s;
        #pragma unroll
        for (int m = 16; m; m >>= 1) sq += __shfl_xor(sq, m);
        Prel[r * 32 + o] = s / fmaxf(sqrtf(sq), 1e-12f);
    }
    if (blockIdx.x == 0 && tid < 32) {
        float s = b_ent[tid];
        #pragma unroll
        for (int j = 0; j < 32; ++j)
            s += b_in[j] * W_ent[tid * 832 + 768 + j] + b_out[j] * W_ent[tid * 832 + 800 + j];
        bprime[tid] = s;
    }
}

// ---------------- scatter: acc[row] += val * P[col] ----------------
__global__ void k_scatter(const int* __restrict__ rows, const int* __restrict__ cols,
                          const float* __restrict__ vals,
                          const float* __restrict__ Ptab, float* __restrict__ accs)
{
    const int stride = gridDim.x * blockDim.x;
    const int total = NNZV << 5;
    for (int g = blockIdx.x * blockDim.x + threadIdx.x; g < total; g += stride) {
        const int c = g & 31;
        const int i = g >> 5;
        const int row = rows[i];
        const int col = cols[i];
        const float v = vals[i] * Ptab[(col << 5) | c];
        atomicAdd(accs + ((row << 5) | c), v);
    }
}

// ---------------- fused: big matvec + normalize + scores ----------------
__global__ __launch_bounds__(1024, 1)
void k_fused(const float* __restrict__ feat_h, const float* __restrict__ feat_p,
             const float* __restrict__ feat_n, const int* __restrict__ eid,
             const float* __restrict__ W_ent, const float* __restrict__ aggY,
             const float* __restrict__ Prel, const float* __restrict__ bprime,
             float* __restrict__ out)
{
    __shared__ float Wlds[32 * 772];  // W_ent[:, :768], row stride 772 (pad)
    const int tid = threadIdx.x;
    for (int idx = tid; idx < 32 * 192; idx += 1024) {
        const int o = idx / 192, j = idx - o * 192;
        float4 v = reinterpret_cast<const float4*>(W_ent)[o * 208 + j];  // 832/4=208
        reinterpret_cast<float4*>(&Wlds[o * 772])[j] = v;
    }
    __syncthreads();

    const int lane = tid & 63;
    const int o    = lane & 31;   // output component owned by this lane
    const int half = lane >> 5;   // k-half
    const int gw   = blockIdx.x * 16 + (tid >> 6);  // 0..4095
    const float* feats[3] = {feat_h, feat_p, feat_n};
    const float4* wp = reinterpret_cast<const float4*>(&Wlds[o * 772 + half * 384]);

    for (int grp = 0; grp < 4; ++grp) {
        const int e0 = gw * 16 + grp * 4;
        float accv[3][4];
        const float4* fp[3][4];
        #pragma unroll
        for (int s = 0; s < 3; ++s)
            #pragma unroll
            for (int e = 0; e < 4; ++e) {
                accv[s][e] = 0.f;
                fp[s][e] = reinterpret_cast<const float4*>(feats[s] + (size_t)(e0 + e) * FEATD) + half * 96;
            }
        #pragma unroll 2
        for (int ch = 0; ch < 96; ++ch) {
            const float4 w = wp[ch];
            #pragma unroll
            for (int s = 0; s < 3; ++s)
                #pragma unroll
                for (int e = 0; e < 4; ++e) {
                    const float4 f = fp[s][e][ch];
                    accv[s][e] += f.x * w.x + f.y * w.y + f.z * w.z + f.w * w.w;
                }
        }
        #pragma unroll
        for (int e = 0; e < 4; ++e) {
            const int ent = e0 + e;
            float y[3];
            #pragma unroll
            for (int s = 0; s < 3; ++s) {
                const float a2 = accv[s][e] + __shfl_xor(accv[s][e], 32);
                float yv = a2 + bprime[o] + aggY[((size_t)s * NB + ent) * 32 + o];
                float sq = yv * yv;
                #pragma unroll
                for (int m = 16; m; m >>= 1) sq += __shfl_xor(sq, m);
                y[s] = yv / fmaxf(sqrtf(sq), 1e-12f);
            }
            const float r  = Prel[(size_t)eid[ent] * 32 + o];
            const float dp = y[0] + r - y[1];
            const float dn = y[0] + r - y[2];
            float sp = dp * dp, sn = dn * dn;
            #pragma unroll
            for (int m = 16; m; m >>= 1) { sp += __shfl_xor(sp, m); sn += __shfl_xor(sn, m); }
            if (lane == 0) { out[ent] = sqrtf(sp); out[NB + ent] = sqrtf(sn); }
        }
    }
}

extern "C" void kernel_launch(void* const* d_in, const int* in_sizes, int n_in,
                              void* d_out, int out_size, void* d_ws, size_t ws_size,
                              hipStream_t stream)
{
    // input order: per p in {h,pos_t,neg_t}: in_rows,in_cols,in_vals,out_rows,out_cols,out_vals,node_feat
    // then eid, rel_emb, W_in, b_in, W_out, b_out, W_ent, b_ent, W_rel, b_rel
    const float* feat_h = (const float*)d_in[6];
    const float* feat_p = (const float*)d_in[13];
    const float* feat_n = (const float*)d_in[20];
    const int*   eid    = (const int*)d_in[21];
    const float* rel_emb = (const float*)d_in[22];
    const float* W_in  = (const float*)d_in[23];
    const float* b_in  = (const float*)d_in[24];
    const float* W_out = (const float*)d_in[25];
    const float* b_out = (const float*)d_in[26];
    const float* W_ent = (const float*)d_in[27];
    const float* b_ent = (const float*)d_in[28];
    const float* W_rel = (const float*)d_in[29];
    const float* b_rel = (const float*)d_in[30];

    float* ws     = (float*)d_ws;
    float* aggY   = ws;                       // 3*NB*32 floats (24 MB)
    float* Pcat   = ws + (size_t)3 * NB * 32; // 2*N_RELS*32
    float* Prel   = Pcat + (size_t)2 * N_RELS * 32;
    float* bprime = Prel + (size_t)N_RELS * 32;

    hipMemsetAsync(aggY, 0, (size_t)3 * NB * 32 * sizeof(float), stream);

    k_prep<<<(3 * N_RELS + 7) / 8, 256, 0, stream>>>(rel_emb, W_in, b_in, W_out, b_out,
                                                     W_ent, b_ent, W_rel, b_rel,
                                                     Pcat, Prel, bprime);

    static const int base_idx[6] = {0, 3, 7, 10, 14, 17};  // h_in,h_out,pos_in,pos_out,neg_in,neg_out
    for (int m = 0; m < 6; ++m) {
        const int d = m & 1, s = m >> 1;
        k_scatter<<<32768, 256, 0, stream>>>((const int*)d_in[base_idx[m]],
                                             (const int*)d_in[base_idx[m] + 1],
                                             (const float*)d_in[base_idx[m] + 2],
                                             Pcat + (size_t)d * N_RELS * 32,
                                             aggY + (size_t)s * NB * 32);
    }

    k_fused<<<256, 1024, 0, stream>>>(feat_h, feat_p, feat_n, eid, W_ent,
                                      aggY, Prel, bprime, (float*)d_out);
}